// Round 1
// baseline (478.288 us; speedup 1.0000x reference)
//
#include <hip/hip_runtime.h>
#include <hip/hip_bf16.h>
#include <stdint.h>

typedef __attribute__((ext_vector_type(8))) short short8;
typedef __attribute__((ext_vector_type(4))) float f32x4;

#define NEGF -3.0e38f
#define NEG  -9.0e15f
#define NSLICE 8
#define SLICE_J 1024
#define CHUNKS 16   // SLICE_J / 64

static __device__ __forceinline__ short f2bf(float f) {
    unsigned int u = __float_as_uint(f);
    u += 0x7fffu + ((u >> 16) & 1u);   // RNE
    return (short)(u >> 16);
}

// ---------------- Phase 1: Wh = h@W  -> e1, e2 (fp32), WhT (bf16, transposed) --
__global__ __launch_bounds__(256)
void gat_wh(const float* __restrict__ h, const float* __restrict__ W,
            const float* __restrict__ a, short* __restrict__ whT,
            float* __restrict__ e1, float* __restrict__ e2)
{
    const int lane = threadIdx.x & 63;
    const int wave = threadIdx.x >> 6;
    const int row0 = blockIdx.x * 32 + wave * 8;

    float acc[8];
#pragma unroll
    for (int r = 0; r < 8; ++r) acc[r] = 0.f;

#pragma unroll 4
    for (int c = 0; c < 512; ++c) {
        const float wv = W[c * 64 + lane];
#pragma unroll
        for (int r = 0; r < 8; ++r)
            acc[r] += h[(size_t)(row0 + r) * 512 + c] * wv;
    }

    const float a1v = a[lane];
    const float a2v = a[64 + lane];
#pragma unroll
    for (int r = 0; r < 8; ++r) {
        float p1 = acc[r] * a1v;
        float p2 = acc[r] * a2v;
#pragma unroll
        for (int off = 32; off; off >>= 1) {
            p1 += __shfl_xor(p1, off);
            p2 += __shfl_xor(p2, off);
        }
        if (lane == 0) { e1[row0 + r] = p1; e2[row0 + r] = p2; }
        whT[(size_t)lane * 8192 + row0 + r] = f2bf(acc[r]);
    }
}

// ---------------- Phase 2: fused masked-softmax + P@Wh (flash-style, split-j) --
__global__ __launch_bounds__(256, 4)
void gat_attn(const int* __restrict__ adj, const short* __restrict__ whT,
              const float* __restrict__ e1, const float* __restrict__ e2,
              float* __restrict__ mpart, float* __restrict__ lpart,
              float* __restrict__ opart)
{
    __shared__ float se2[SLICE_J];
    const int bid = blockIdx.x;
    const int s   = bid & (NSLICE - 1);
    const int rb  = bid >> 3;
    const int tid = threadIdx.x;

    // stage e2 slice into LDS (1024 floats)
    {
        const float4 v = *reinterpret_cast<const float4*>(e2 + s * SLICE_J + tid * 4);
        *reinterpret_cast<float4*>(se2 + tid * 4) = v;
    }
    __syncthreads();

    const int lane = tid & 63;
    const int wave = tid >> 6;
    const int quad = lane >> 4;
    const int r16  = lane & 15;
    const int rowBase = rb * 64 + wave * 16;
    const int row  = rowBase + r16;
    const float e1v = e1[row];
    const size_t adjRow = (size_t)row * 8192 + (size_t)s * SLICE_J;

    float m = NEGF, l = 0.f;
    f32x4 acc[4];
#pragma unroll
    for (int f = 0; f < 4; ++f) acc[f] = (f32x4){0.f, 0.f, 0.f, 0.f};

    for (int ch = 0; ch < CHUNKS; ++ch) {
        const int j0 = ch * 64 + quad * 8;   // within-slice, this lane's k-group (frag0)
        // adj in A-fragment layout: m=r16, k=quad*8+t (frag0), +32 (frag1)
        const int4 A0 = *reinterpret_cast<const int4*>(adj + adjRow + j0);
        const int4 A1 = *reinterpret_cast<const int4*>(adj + adjRow + j0 + 4);
        const int4 A2 = *reinterpret_cast<const int4*>(adj + adjRow + j0 + 32);
        const int4 A3 = *reinterpret_cast<const int4*>(adj + adjRow + j0 + 36);
        const float4 E0 = *reinterpret_cast<const float4*>(se2 + j0);
        const float4 E1 = *reinterpret_cast<const float4*>(se2 + j0 + 4);
        const float4 E2 = *reinterpret_cast<const float4*>(se2 + j0 + 32);
        const float4 E3 = *reinterpret_cast<const float4*>(se2 + j0 + 36);

        const int   av[16] = {A0.x,A0.y,A0.z,A0.w, A1.x,A1.y,A1.z,A1.w,
                              A2.x,A2.y,A2.z,A2.w, A3.x,A3.y,A3.z,A3.w};
        const float ev[16] = {E0.x,E0.y,E0.z,E0.w, E1.x,E1.y,E1.z,E1.w,
                              E2.x,E2.y,E2.z,E2.w, E3.x,E3.y,E3.z,E3.w};
        float sc[16];
#pragma unroll
        for (int t = 0; t < 16; ++t) {
            float x = e1v + ev[t];
            x = fmaxf(x, 0.f) + 0.2f * fminf(x, 0.f);   // leaky relu
            sc[t] = (av[t] > 0) ? x : NEG;
        }
        float cmax = sc[0];
#pragma unroll
        for (int t = 1; t < 16; ++t) cmax = fmaxf(cmax, sc[t]);
        cmax = fmaxf(cmax, __shfl_xor(cmax, 16));
        cmax = fmaxf(cmax, __shfl_xor(cmax, 32));

        const float mn = fmaxf(m, cmax);
        const float alpha = __expf(m - mn);   // m=NEGF first iter -> 0

        float w[16];
        float wsum = 0.f;
#pragma unroll
        for (int t = 0; t < 16; ++t) { w[t] = __expf(sc[t] - mn); wsum += w[t]; }
        wsum += __shfl_xor(wsum, 16);
        wsum += __shfl_xor(wsum, 32);
        l = l * alpha + wsum;
        m = mn;

        short8 af0, af1;
#pragma unroll
        for (int t = 0; t < 8; ++t) { af0[t] = f2bf(w[t]); af1[t] = f2bf(w[t + 8]); }

        // rescale O: D-layout row = quad*4+rg, its alpha lives at lane==row (r16==row)
#pragma unroll
        for (int rg = 0; rg < 4; ++rg) {
            const float ar = __shfl(alpha, quad * 4 + rg);
#pragma unroll
            for (int f = 0; f < 4; ++f) acc[f][rg] *= ar;
        }

        const size_t jg = (size_t)s * SLICE_J + ch * 64 + quad * 8;
#pragma unroll
        for (int f = 0; f < 4; ++f) {
            const short8 b0 = *reinterpret_cast<const short8*>(whT + (size_t)(f * 16 + r16) * 8192 + jg);
            const short8 b1 = *reinterpret_cast<const short8*>(whT + (size_t)(f * 16 + r16) * 8192 + jg + 32);
            acc[f] = __builtin_amdgcn_mfma_f32_16x16x32_bf16(af0, b0, acc[f], 0, 0, 0);
            acc[f] = __builtin_amdgcn_mfma_f32_16x16x32_bf16(af1, b1, acc[f], 0, 0, 0);
        }
    }

    // partial outputs
    if (lane < 16) {
        mpart[s * 8192 + rowBase + lane] = m;   // lane<16 has r16==lane
        lpart[s * 8192 + rowBase + lane] = l;
    }
#pragma unroll
    for (int f = 0; f < 4; ++f) {
#pragma unroll
        for (int rg = 0; rg < 4; ++rg) {
            const int orow = rowBase + quad * 4 + rg;
            const int ocol = f * 16 + r16;
            opart[((size_t)s * 8192 + orow) * 64 + ocol] = acc[f][rg];
        }
    }
}

// ---------------- Phase 3: merge slice partials, normalize, ELU ----------------
__global__ __launch_bounds__(256)
void gat_combine(const float* __restrict__ mpart, const float* __restrict__ lpart,
                 const float* __restrict__ opart, float* __restrict__ out)
{
    const int gid = blockIdx.x * 256 + threadIdx.x;
    const int row = gid >> 6;
    const int f   = gid & 63;

    float ms[NSLICE];
    float mstar = NEGF;
#pragma unroll
    for (int s = 0; s < NSLICE; ++s) {
        ms[s] = mpart[s * 8192 + row];
        mstar = fmaxf(mstar, ms[s]);
    }
    float osum = 0.f, lsum = 0.f;
#pragma unroll
    for (int s = 0; s < NSLICE; ++s) {
        const float wgt = __expf(ms[s] - mstar);
        lsum += lpart[s * 8192 + row] * wgt;
        osum += opart[((size_t)s * 8192 + row) * 64 + f] * wgt;
    }
    const float v = osum / lsum;
    out[gid] = (v > 0.f) ? v : (__expf(v) - 1.f);
}

extern "C" void kernel_launch(void* const* d_in, const int* in_sizes, int n_in,
                              void* d_out, int out_size, void* d_ws, size_t ws_size,
                              hipStream_t stream) {
    const float* h   = (const float*)d_in[0];
    const int*   adj = (const int*)d_in[1];
    const float* W   = (const float*)d_in[2];
    const float* a   = (const float*)d_in[3];
    float* out = (float*)d_out;

    char* ws = (char*)d_ws;
    short* whT   = (short*)ws;                                   // 64*8192*2  = 1 MB
    float* e1    = (float*)(ws + (1u << 20));                    // 32 KB
    float* e2    = (float*)(ws + (1u << 20) + (32u << 10));      // 32 KB
    float* mpart = (float*)(ws + (1u << 20) + (64u << 10));      // 256 KB
    float* lpart = (float*)(ws + (1u << 20) + (320u << 10));     // 256 KB
    float* opart = (float*)(ws + (1u << 20) + (576u << 10));     // 16 MB

    gat_wh<<<256, 256, 0, stream>>>(h, W, a, whT, e1, e2);
    gat_attn<<<128 * NSLICE, 256, 0, stream>>>(adj, whT, e1, e2, mpart, lpart, opart);
    gat_combine<<<out_size / 256, 256, 0, stream>>>(mpart, lpart, opart, out);
}

// Round 3
// 442.027 us; speedup vs baseline: 1.0820x; 1.0820x over previous
//
#include <hip/hip_runtime.h>
#include <hip/hip_bf16.h>
#include <stdint.h>

typedef __attribute__((ext_vector_type(8))) short short8;
typedef __attribute__((ext_vector_type(4))) float f32x4;

#define NSLICE 8
#define SLICE_J 1024
#define CHUNKS 16   // SLICE_J / 64
#define L2E 1.44269504f

static __device__ __forceinline__ short f2bf(float f) {
    unsigned int u = __float_as_uint(f);
    u += 0x7fffu + ((u >> 16) & 1u);   // RNE
    return (short)(u >> 16);
}

// w = exp2(lrelu(e1s + e2s)) if a>0 else 0; accumulate lsum; return bf16(w).
// e1s/e2s are pre-scaled by log2(e), so exp2(lrelu(scaled)) == exp(lrelu(raw)).
static __device__ __forceinline__ short welem(int a, float e2s, float e1s, float& lsum) {
    float x = e1s + e2s;
    x = fmaxf(x, 0.f) + 0.2f * fminf(x, 0.f);    // leaky relu (scale-invariant)
    float w = __builtin_amdgcn_exp2f(x);          // v_exp_f32 (2^x)
    w = (a > 0) ? w : 0.f;
    lsum += w;
    return f2bf(w);
}

// ---------------- Phase 1: Wh = h@W -> e1, e2 (fp32), WhT (bf16, transposed) --
__global__ __launch_bounds__(256)
void gat_wh(const float* __restrict__ h, const float* __restrict__ W,
            const float* __restrict__ a, short* __restrict__ whT,
            float* __restrict__ e1, float* __restrict__ e2)
{
    const int lane = threadIdx.x & 63;
    const int wave = threadIdx.x >> 6;
    const int row0 = blockIdx.x * 16 + wave * 4;   // 512 blocks x 4 waves x 4 rows

    float acc[4] = {0.f, 0.f, 0.f, 0.f};
#pragma unroll 8
    for (int c = 0; c < 512; ++c) {
        const float wv = W[c * 64 + lane];          // coalesced
#pragma unroll
        for (int r = 0; r < 4; ++r)                 // h index wave-uniform -> s_load
            acc[r] += h[(size_t)(row0 + r) * 512 + c] * wv;
    }

    const float a1v = a[lane];
    const float a2v = a[64 + lane];
#pragma unroll
    for (int r = 0; r < 4; ++r) {
        float p1 = acc[r] * a1v;
        float p2 = acc[r] * a2v;
#pragma unroll
        for (int off = 32; off; off >>= 1) {
            p1 += __shfl_xor(p1, off);
            p2 += __shfl_xor(p2, off);
        }
        if (lane == 0) { e1[row0 + r] = p1; e2[row0 + r] = p2; }
        whT[(size_t)lane * 8192 + row0 + r] = f2bf(acc[r]);
    }
}

// ---------------- Phase 2: fused masked exp + P@Wh (no-max softmax, split-j) --
__global__ __launch_bounds__(256)
void gat_attn(const int* __restrict__ adj, const short* __restrict__ whT,
              const float* __restrict__ e1, const float* __restrict__ e2,
              float* __restrict__ lpart, float* __restrict__ opart)
{
    __shared__ float se2[SLICE_J];
    const int bid = blockIdx.x;
    const int s   = bid & (NSLICE - 1);
    const int rb  = bid >> 3;
    const int tid = threadIdx.x;

    // stage e2 slice into LDS, pre-scaled by log2(e)
    {
        float4 v = *reinterpret_cast<const float4*>(e2 + s * SLICE_J + tid * 4);
        v.x *= L2E; v.y *= L2E; v.z *= L2E; v.w *= L2E;
        *reinterpret_cast<float4*>(se2 + tid * 4) = v;
    }
    __syncthreads();

    const int lane = tid & 63;
    const int wave = tid >> 6;
    const int quad = lane >> 4;
    const int r16  = lane & 15;
    const int rowBase = rb * 64 + wave * 16;
    const int row  = rowBase + r16;
    const float e1s = e1[row] * L2E;
    const size_t adjRow = (size_t)row * 8192 + (size_t)s * SLICE_J;

    float lsum = 0.f;
    f32x4 acc[4];
#pragma unroll
    for (int f = 0; f < 4; ++f) acc[f] = (f32x4){0.f, 0.f, 0.f, 0.f};

    for (int ch = 0; ch < CHUNKS; ++ch) {
        const int j0 = ch * 64 + quad * 8;   // within-slice k-group for A-frag
        // adj directly in MFMA A-fragment layout: m=r16, k=quad*8+t (+32 for frag1)
        const int4 A0 = *reinterpret_cast<const int4*>(adj + adjRow + j0);
        const int4 A1 = *reinterpret_cast<const int4*>(adj + adjRow + j0 + 4);
        const int4 A2 = *reinterpret_cast<const int4*>(adj + adjRow + j0 + 32);
        const int4 A3 = *reinterpret_cast<const int4*>(adj + adjRow + j0 + 36);
        const float4 E0 = *reinterpret_cast<const float4*>(se2 + j0);
        const float4 E1 = *reinterpret_cast<const float4*>(se2 + j0 + 4);
        const float4 E2 = *reinterpret_cast<const float4*>(se2 + j0 + 32);
        const float4 E3 = *reinterpret_cast<const float4*>(se2 + j0 + 36);

        short8 af0, af1;
        af0[0] = welem(A0.x, E0.x, e1s, lsum);
        af0[1] = welem(A0.y, E0.y, e1s, lsum);
        af0[2] = welem(A0.z, E0.z, e1s, lsum);
        af0[3] = welem(A0.w, E0.w, e1s, lsum);
        af0[4] = welem(A1.x, E1.x, e1s, lsum);
        af0[5] = welem(A1.y, E1.y, e1s, lsum);
        af0[6] = welem(A1.z, E1.z, e1s, lsum);
        af0[7] = welem(A1.w, E1.w, e1s, lsum);
        af1[0] = welem(A2.x, E2.x, e1s, lsum);
        af1[1] = welem(A2.y, E2.y, e1s, lsum);
        af1[2] = welem(A2.z, E2.z, e1s, lsum);
        af1[3] = welem(A2.w, E2.w, e1s, lsum);
        af1[4] = welem(A3.x, E3.x, e1s, lsum);
        af1[5] = welem(A3.y, E3.y, e1s, lsum);
        af1[6] = welem(A3.z, E3.z, e1s, lsum);
        af1[7] = welem(A3.w, E3.w, e1s, lsum);

        const size_t jg = (size_t)s * SLICE_J + ch * 64 + quad * 8;
#pragma unroll
        for (int f = 0; f < 4; ++f) {
            const short8 b0 = *reinterpret_cast<const short8*>(whT + (size_t)(f * 16 + r16) * 8192 + jg);
            const short8 b1 = *reinterpret_cast<const short8*>(whT + (size_t)(f * 16 + r16) * 8192 + jg + 32);
            acc[f] = __builtin_amdgcn_mfma_f32_16x16x32_bf16(af0, b0, acc[f], 0, 0, 0);
            acc[f] = __builtin_amdgcn_mfma_f32_16x16x32_bf16(af1, b1, acc[f], 0, 0, 0);
        }
    }

    // denominator partial: reduce across the 4 quads holding the same row
    lsum += __shfl_xor(lsum, 16);
    lsum += __shfl_xor(lsum, 32);
    if (lane < 16) lpart[s * 8192 + rowBase + lane] = lsum;

#pragma unroll
    for (int f = 0; f < 4; ++f) {
#pragma unroll
        for (int rg = 0; rg < 4; ++rg) {
            const int orow = rowBase + quad * 4 + rg;
            const int ocol = f * 16 + r16;
            opart[((size_t)s * 8192 + orow) * 64 + ocol] = acc[f][rg];
        }
    }
}

// ---------------- Phase 3: merge slice partials, normalize, ELU ----------------
__global__ __launch_bounds__(256)
void gat_combine(const float* __restrict__ lpart, const float* __restrict__ opart,
                 float* __restrict__ out)
{
    const int gid = blockIdx.x * 256 + threadIdx.x;
    const int row = gid >> 6;
    const int f   = gid & 63;

    float lsum = 0.f, osum = 0.f;
#pragma unroll
    for (int s = 0; s < NSLICE; ++s) {
        lsum += lpart[s * 8192 + row];
        osum += opart[((size_t)s * 8192 + row) * 64 + f];
    }
    const float v = osum / lsum;
    out[gid] = (v > 0.f) ? v : (__expf(v) - 1.f);
}

extern "C" void kernel_launch(void* const* d_in, const int* in_sizes, int n_in,
                              void* d_out, int out_size, void* d_ws, size_t ws_size,
                              hipStream_t stream) {
    const float* h   = (const float*)d_in[0];
    const int*   adj = (const int*)d_in[1];
    const float* W   = (const float*)d_in[2];
    const float* a   = (const float*)d_in[3];
    float* out = (float*)d_out;

    char* ws = (char*)d_ws;
    short* whT   = (short*)ws;                                   // 1 MB
    float* e1    = (float*)(ws + (1u << 20));                    // 32 KB
    float* e2    = (float*)(ws + (1u << 20) + (32u << 10));      // 32 KB
    float* lpart = (float*)(ws + (1u << 20) + (64u << 10));      // 256 KB
    float* opart = (float*)(ws + (2u << 20));                    // 16 MB

    gat_wh<<<512, 256, 0, stream>>>(h, W, a, whT, e1, e2);
    gat_attn<<<128 * NSLICE, 256, 0, stream>>>(adj, whT, e1, e2, lpart, opart);
    gat_combine<<<out_size / 256, 256, 0, stream>>>(lpart, opart, out);
}

// Round 4
// 434.400 us; speedup vs baseline: 1.1010x; 1.0176x over previous
//
#include <hip/hip_runtime.h>
#include <hip/hip_bf16.h>
#include <stdint.h>

typedef __attribute__((ext_vector_type(8))) short short8;
typedef __attribute__((ext_vector_type(4))) float f32x4;

#define NSLICE 8
#define SLICE_J 1024
#define CHUNKS 16   // SLICE_J / 64
#define L2E 1.44269504f

static __device__ __forceinline__ short f2bf(float f) {
    unsigned int u = __float_as_uint(f);
    u += 0x7fffu + ((u >> 16) & 1u);   // RNE
    return (short)(u >> 16);
}

// w = exp2(lrelu(e1s + e2s)) if a>0 else 0; accumulate lsum; return bf16(w).
static __device__ __forceinline__ short welem(int a, float e2s, float e1s, float& lsum) {
    float x = e1s + e2s;
    x = fmaxf(x, 0.f) + 0.2f * fminf(x, 0.f);    // leaky relu (scale-invariant)
    float w = __builtin_amdgcn_exp2f(x);          // v_exp_f32 (2^x)
    w = (a > 0) ? w : 0.f;
    lsum += w;
    return f2bf(w);
}

// ---------------- Phase 1: Wh = h@W -> e1, e2 (fp32), whT in B-fragment tiles --
// whT layout (shorts): tile(=j>>6)*4096 + ((n>>4)*2 + frag)*512 + qk*128 + (n&15)*8 + t
//   where j = node, n = feature, kin = j&63, frag = kin>>5, qk = (kin>>3)&3, t = kin&7.
// This makes every phase-2 B-fragment load 64 lanes x 16 B CONTIGUOUS.
__global__ __launch_bounds__(256)
void gat_wh(const float* __restrict__ h, const float* __restrict__ W,
            const float* __restrict__ a, short* __restrict__ whT,
            float* __restrict__ e1, float* __restrict__ e2)
{
    const int lane = threadIdx.x & 63;
    const int wave = threadIdx.x >> 6;
    const int row0 = blockIdx.x * 16 + wave * 4;   // 512 blocks x 4 waves x 4 rows

    float acc[4] = {0.f, 0.f, 0.f, 0.f};
#pragma unroll 8
    for (int c = 0; c < 512; ++c) {
        const float wv = W[c * 64 + lane];          // coalesced
#pragma unroll
        for (int r = 0; r < 4; ++r)                 // h index wave-uniform -> s_load
            acc[r] += h[(size_t)(row0 + r) * 512 + c] * wv;
    }

    const float a1v = a[lane];
    const float a2v = a[64 + lane];
    const int f    = lane >> 4;
    const int r16n = lane & 15;
#pragma unroll
    for (int r = 0; r < 4; ++r) {
        float p1 = acc[r] * a1v;
        float p2 = acc[r] * a2v;
#pragma unroll
        for (int off = 32; off; off >>= 1) {
            p1 += __shfl_xor(p1, off);
            p2 += __shfl_xor(p2, off);
        }
        if (lane == 0) { e1[row0 + r] = p1; e2[row0 + r] = p2; }
        const int j = row0 + r;
        const int kin = j & 63;
        const int frag = (kin >> 5) & 1, qk = (kin >> 3) & 3, t = kin & 7;
        whT[(size_t)(j >> 6) * 4096 + (f * 2 + frag) * 512 + qk * 128 + r16n * 8 + t]
            = f2bf(acc[r]);
    }
}

// ---------------- Phase 2: fused masked exp + P@Wh (no-max softmax, split-j) --
__global__ __launch_bounds__(256)
void gat_attn(const int* __restrict__ adj, const short* __restrict__ whT,
              const float* __restrict__ e1, const float* __restrict__ e2,
              float* __restrict__ lpart, float* __restrict__ opart)
{
    __shared__ float se2[SLICE_J];
    const int bid = blockIdx.x;
    const int s   = bid & (NSLICE - 1);
    const int rb  = bid >> 3;
    const int tid = threadIdx.x;

    // stage e2 slice into LDS, pre-scaled by log2(e)
    {
        float4 v = *reinterpret_cast<const float4*>(e2 + s * SLICE_J + tid * 4);
        v.x *= L2E; v.y *= L2E; v.z *= L2E; v.w *= L2E;
        *reinterpret_cast<float4*>(se2 + tid * 4) = v;
    }
    __syncthreads();

    const int lane = tid & 63;
    const int wave = tid >> 6;
    const int quad = lane >> 4;
    const int r16  = lane & 15;
    const int rowBase = rb * 64 + wave * 16;
    const int row  = rowBase + r16;
    const float e1s = e1[row] * L2E;
    const size_t adjRow = (size_t)row * 8192 + (size_t)s * SLICE_J;

    float lsum = 0.f;
    f32x4 acc[4];
#pragma unroll
    for (int ff = 0; ff < 4; ++ff) acc[ff] = (f32x4){0.f, 0.f, 0.f, 0.f};

    for (int ch = 0; ch < CHUNKS; ++ch) {
        const int j0 = ch * 64 + quad * 8;   // within-slice k-group for A-frag
        // adj directly in MFMA A-fragment layout: m=r16, k=quad*8+t (+32 for frag1)
        const int4 A0 = *reinterpret_cast<const int4*>(adj + adjRow + j0);
        const int4 A1 = *reinterpret_cast<const int4*>(adj + adjRow + j0 + 4);
        const int4 A2 = *reinterpret_cast<const int4*>(adj + adjRow + j0 + 32);
        const int4 A3 = *reinterpret_cast<const int4*>(adj + adjRow + j0 + 36);
        const float4 E0 = *reinterpret_cast<const float4*>(se2 + j0);
        const float4 E1 = *reinterpret_cast<const float4*>(se2 + j0 + 4);
        const float4 E2 = *reinterpret_cast<const float4*>(se2 + j0 + 32);
        const float4 E3 = *reinterpret_cast<const float4*>(se2 + j0 + 36);

        short8 af0, af1;
        af0[0] = welem(A0.x, E0.x, e1s, lsum);
        af0[1] = welem(A0.y, E0.y, e1s, lsum);
        af0[2] = welem(A0.z, E0.z, e1s, lsum);
        af0[3] = welem(A0.w, E0.w, e1s, lsum);
        af0[4] = welem(A1.x, E1.x, e1s, lsum);
        af0[5] = welem(A1.y, E1.y, e1s, lsum);
        af0[6] = welem(A1.z, E1.z, e1s, lsum);
        af0[7] = welem(A1.w, E1.w, e1s, lsum);
        af1[0] = welem(A2.x, E2.x, e1s, lsum);
        af1[1] = welem(A2.y, E2.y, e1s, lsum);
        af1[2] = welem(A2.z, E2.z, e1s, lsum);
        af1[3] = welem(A2.w, E2.w, e1s, lsum);
        af1[4] = welem(A3.x, E3.x, e1s, lsum);
        af1[5] = welem(A3.y, E3.y, e1s, lsum);
        af1[6] = welem(A3.z, E3.z, e1s, lsum);
        af1[7] = welem(A3.w, E3.w, e1s, lsum);

        // B-fragment loads: whT pre-permuted -> 64 lanes x 16 B contiguous per load
        const short* wtile = whT + (size_t)(s * 16 + ch) * 4096 + lane * 8;
#pragma unroll
        for (int ff = 0; ff < 4; ++ff) {
            const short8 b0 = *reinterpret_cast<const short8*>(wtile + (ff * 2 + 0) * 512);
            const short8 b1 = *reinterpret_cast<const short8*>(wtile + (ff * 2 + 1) * 512);
            acc[ff] = __builtin_amdgcn_mfma_f32_16x16x32_bf16(af0, b0, acc[ff], 0, 0, 0);
            acc[ff] = __builtin_amdgcn_mfma_f32_16x16x32_bf16(af1, b1, acc[ff], 0, 0, 0);
        }
    }

    // denominator partial: reduce across the 4 quads holding the same row
    lsum += __shfl_xor(lsum, 16);
    lsum += __shfl_xor(lsum, 32);
    if (lane < 16) lpart[s * 8192 + rowBase + lane] = lsum;

#pragma unroll
    for (int ff = 0; ff < 4; ++ff) {
#pragma unroll
        for (int rg = 0; rg < 4; ++rg) {
            const int orow = rowBase + quad * 4 + rg;
            const int ocol = ff * 16 + r16;
            opart[((size_t)s * 8192 + orow) * 64 + ocol] = acc[ff][rg];
        }
    }
}

// ---------------- Phase 3: merge slice partials, normalize, ELU ----------------
__global__ __launch_bounds__(256)
void gat_combine(const float* __restrict__ lpart, const float* __restrict__ opart,
                 float* __restrict__ out)
{
    const int gid = blockIdx.x * 256 + threadIdx.x;
    const int row = gid >> 6;
    const int f   = gid & 63;

    float lsum = 0.f, osum = 0.f;
#pragma unroll
    for (int s = 0; s < NSLICE; ++s) {
        lsum += lpart[s * 8192 + row];
        osum += opart[((size_t)s * 8192 + row) * 64 + f];
    }
    const float v = osum / lsum;
    out[gid] = (v > 0.f) ? v : (__expf(v) - 1.f);
}

extern "C" void kernel_launch(void* const* d_in, const int* in_sizes, int n_in,
                              void* d_out, int out_size, void* d_ws, size_t ws_size,
                              hipStream_t stream) {
    const float* h   = (const float*)d_in[0];
    const int*   adj = (const int*)d_in[1];
    const float* W   = (const float*)d_in[2];
    const float* a   = (const float*)d_in[3];
    float* out = (float*)d_out;

    char* ws = (char*)d_ws;
    short* whT   = (short*)ws;                                   // 1 MB
    float* e1    = (float*)(ws + (1u << 20));                    // 32 KB
    float* e2    = (float*)(ws + (1u << 20) + (32u << 10));      // 32 KB
    float* lpart = (float*)(ws + (1u << 20) + (64u << 10));      // 256 KB
    float* opart = (float*)(ws + (2u << 20));                    // 16 MB

    gat_wh<<<512, 256, 0, stream>>>(h, W, a, whT, e1, e2);
    gat_attn<<<128 * NSLICE, 256, 0, stream>>>(adj, whT, e1, e2, lpart, opart);
    gat_combine<<<out_size / 256, 256, 0, stream>>>(lpart, opart, out);
}